// Round 9
// baseline (181.572 us; speedup 1.0000x reference)
//
#include <hip/hip_runtime.h>

// OneDilate: out[b,c,i,j] = 50 - 0.5 * sum_{10x10 clamped window} x
// Separable, V-only-LDS kernel.
//  B1: each thread reads 11 independent float4s straight from GLOBAL (its
//      column-group, rows clamp(i0-4..i0+6)) -- input is L2/L3-resident
//      (FETCH=49MB across rounds), so LDS-staging it was pure overhead
//      (rounds 6-8 pinned at 60-65us while VALU/LDS work varied 3x: the
//      limiter is load-issue duty cycle, not any pipe).
//      Vertical 10-sums -> 2 V rows -> 32KB LDS.
//  B2: proven horizontal 10-sum code reads V, stores 2 output rows.
//  One __syncthreads per block; stores never drained (block exits).
//  launch_bounds(1024,8): VGPR<=64 -> 2 blocks/CU co-resident, so one
//  block's load burst overlaps the other's store drain. Live set ~55 regs.

#define IMG 512
#define OUTW 511
#define KS 10
#define MEAN 4
#define SUBB 16                  // output rows per block
#define ROWF4 (IMG / 4)          // 128 float4 per row
#define NTHREADS 1024
#define NBANDS (IMG / SUBB)      // 32
#define NIMG 96                  // 32 * 3 images
#define NWG (NBANDS * NIMG)      // 3072 (divisible by 8 XCDs)
#define CPX (NWG / 8)            // 384 per XCD chunk

__device__ __forceinline__ float4 f4add(float4 a, float4 b) {
    return make_float4(a.x + b.x, a.y + b.y, a.z + b.z, a.w + b.w);
}

__global__ __launch_bounds__(NTHREADS, 8) void onedilate_kernel(
    const float* __restrict__ x, float* __restrict__ out)
{
    __shared__ float Vb[SUBB * IMG];   // 32 KiB: 16 rows of vertical 10-sums

    // Bijective XCD-aware swizzle: each XCD owns a contiguous chunk of
    // (band, image); consecutive blocks in a chunk = adjacent bands of the
    // same image -> 9-row vertical halo re-reads hit that XCD's L2.
    const int lin = blockIdx.y * NBANDS + blockIdx.x;
    const int swz = (lin & 7) * CPX + (lin >> 3);
    const int bx  = swz & (NBANDS - 1);  // band
    const int bc  = swz >> 5;            // image (NBANDS == 32)

    const int tid = threadIdx.x;
    const int jc  = tid & (ROWF4 - 1);   // float4 col group 0..127
    const int rg  = tid >> 7;            // row group 0..7 (2 rows each)
    const int rb  = bx * SUBB;           // first output row of this band

    const float* __restrict__ xim = x + (size_t)bc * (IMG * IMG);
    float* __restrict__ oim = out + (size_t)bc * (OUTW * OUTW);

    // ---------- B1: vertical 10-sums, global -> LDS ----------
    // Thread covers V rows vr0=2rg, vr0+1 (abs out rows i0, i0+1):
    //   V[i] = sum_{d=-4..5} x[clamp(i+d)]; needs x rows i0-4 .. i0+6.
    {
        const int i0 = rb + 2 * rg;
        const float* cp = xim + jc * 4;
#define TROW(k_) (*(const float4*)(cp + (size_t)min(max(i0 - MEAN + (k_), 0), IMG - 1) * IMG))
        const float4 t0  = TROW(0);
        const float4 t1  = TROW(1);
        const float4 t2  = TROW(2);
        const float4 t3  = TROW(3);
        const float4 t4  = TROW(4);
        const float4 t5  = TROW(5);
        const float4 t6  = TROW(6);
        const float4 t7  = TROW(7);
        const float4 t8  = TROW(8);
        const float4 t9  = TROW(9);
        const float4 t10 = TROW(10);
#undef TROW
        // Tree sum of t0..t9 (10-window for row i0).
        const float4 s01 = f4add(t0, t1), s23 = f4add(t2, t3);
        const float4 s45 = f4add(t4, t5), s67 = f4add(t6, t7);
        const float4 s89 = f4add(t8, t9);
        const float4 v0 = f4add(f4add(f4add(s01, s23), f4add(s45, s67)), s89);
        const float4 v1 = make_float4(v0.x + t10.x - t0.x, v0.y + t10.y - t0.y,
                                      v0.z + t10.z - t0.z, v0.w + t10.w - t0.w);
        float4* Vv = (float4*)Vb;
        Vv[(2 * rg + 0) * ROWF4 + jc] = v0;
        Vv[(2 * rg + 1) * ROWF4 + jc] = v1;
    }
    __syncthreads();

    // ---------- B2: horizontal 10-sums, LDS -> out ----------
    const int cbase = 4 * jc;
    const int bl0 = max(cbase - 4, 0);        // only jc=0 OOB-low
    const int bl2 = min(cbase + 4, IMG - 4);  // only jc=127 OOB-high
    const int bl3 = min(cbase + 8, IMG - 4);  // jc=126,127 OOB-high
    const bool lo0 = (cbase - 4 < 0);
    const bool hi2 = (cbase + 4 > IMG - 4);
    const bool hi3 = (cbase + 8 > IMG - 4);

#pragma unroll
    for (int k = 0; k < 2; ++k) {
        const int r = 2 * rg + k;             // local V row
        const float* rp = Vb + r * IMG;
        float4 v0 = *(const float4*)(rp + bl0);
        float4 v1 = *(const float4*)(rp + cbase);
        float4 v2 = *(const float4*)(rp + bl2);
        float4 v3 = *(const float4*)(rp + bl3);
        if (lo0) v0 = make_float4(v0.x, v0.x, v0.x, v0.x);  // col 0 replicate
        if (hi2) v2 = make_float4(v2.w, v2.w, v2.w, v2.w);  // col 511 replicate
        const float w12 = hi3 ? v3.w : v3.x;                // col min(4jc+8,511)

        const float S = ((v0.x + v0.y) + (v0.z + v0.w))
                      + ((v1.x + v1.y) + (v1.z + v1.w))
                      + (v2.x + v2.y);
        const float d1  = v2.z - v0.x;
        const float d2  = v2.w - v0.y;
        const float d3  = w12  - v0.z;
        const float d12 = d1 + d2;

        const int i = rb + r;
        if (i < OUTW) {                       // only band 31's row 15 fails
            float* op = oim + (size_t)i * OUTW + cbase;
            op[0] = fmaf(S, -0.5f, 50.0f);
            op[1] = fmaf(S + d1, -0.5f, 50.0f);
            op[2] = fmaf(S + d12, -0.5f, 50.0f);
            if (cbase + 3 < OUTW)
                op[3] = fmaf(S + (d12 + d3), -0.5f, 50.0f);
        }
    }
}

extern "C" void kernel_launch(void* const* d_in, const int* in_sizes, int n_in,
                              void* d_out, int out_size, void* d_ws, size_t ws_size,
                              hipStream_t stream) {
    const float* x = (const float*)d_in[0];
    float* out = (float*)d_out;

    dim3 block(NTHREADS, 1, 1);
    dim3 grid(NBANDS, NIMG, 1);   // 32 x 96 = 3072 blocks
    onedilate_kernel<<<grid, block, 0, stream>>>(x, out);
}